// Round 6
// baseline (103.258 us; speedup 1.0000x reference)
//
#include <hip/hip_runtime.h>

typedef float f32x4 __attribute__((ext_vector_type(4)));

// x: [1, 2049, 8192] f32 ; lambda: [1, 8192] f32
// out: [1, 1+2048+8192, 8192] f32
//   row 0           : center = lam*x0 - 0.5*lam*lower
//   rows 1..2048    : x[e]*lam
//   rows 2049..10240: one value per crossing column at row cumsum(has)-1, else 0

// K-mega: blocks [0, k1Blocks) = fused errs-scale + per-chunk abs partials
//         blocks [k1Blocks, ..) = linear NT zero-fill of the extra region.
// The zero-fill depends on NOTHING, so it runs concurrently with the
// reduction pass instead of waiting behind the scan.
__global__ __launch_bounds__(256) void k_mega(
    const float* __restrict__ x, const float* __restrict__ lam,
    float* __restrict__ out, float* __restrict__ partials,
    float* __restrict__ outExtra,
    int N, int rowsPerChunk, int k1Blocks, int fillRowsPerBlock)
{
    const int t = threadIdx.x;
    if ((int)blockIdx.x < k1Blocks) {
        const int bx = blockIdx.x;
        const int nxb = N / 1024;                 // 8
        const int xb = bx % nxb;
        const int yb = bx / nxb;
        const int col = (xb * 256 + t) * 4;
        const int r0  = 1 + yb * rowsPerChunk;
        const f32x4 l4 = *(const f32x4*)(lam + col);
        f32x4 acc = {0.f, 0.f, 0.f, 0.f};
        #pragma unroll 4
        for (int r = r0; r < r0 + rowsPerChunk; ++r) {
            const f32x4 v = __builtin_nontemporal_load((const f32x4*)(x + (size_t)r * N + col));
            acc.x += fabsf(v.x); acc.y += fabsf(v.y); acc.z += fabsf(v.z); acc.w += fabsf(v.w);
            __builtin_nontemporal_store(v * l4, (f32x4*)(out + (size_t)r * N + col));
        }
        *(f32x4*)(partials + (size_t)yb * N + col) = acc;
    } else {
        // Linear zero-fill: this block owns fillRowsPerBlock contiguous rows.
        const int fb = blockIdx.x - k1Blocks;
        float* base = outExtra + (size_t)fb * fillRowsPerBlock * N;
        const int total4 = fillRowsPerBlock * (N / 4);   // f32x4 slots
        const f32x4 z = {0.f, 0.f, 0.f, 0.f};
        #pragma unroll 4
        for (int i = t; i < total4; i += 256)
            __builtin_nontemporal_store(z, (f32x4*)base + i);
    }
}

// K2: reduce partials per column, write center (out row 0), flags, vals.
__global__ __launch_bounds__(256) void k_stats(
    const float* __restrict__ x, const float* __restrict__ lam,
    const float* __restrict__ partials,
    float* __restrict__ out, float* __restrict__ vals, int* __restrict__ flags,
    int N, int P)
{
    const int n = blockIdx.x * 256 + threadIdx.x;
    float s = 0.f;
    for (int p = 0; p < P; ++p) s += partials[(size_t)p * N + n];
    const float x0 = x[n];          // row 0 of x
    const float l  = lam[n];
    const float lower = x0 - s;
    const float upper = x0 + s;
    out[n] = l * x0 - l * lower * 0.5f;          // center
    const bool has = (lower < 0.f) && (upper > 0.f);
    flags[n] = has ? 1 : 0;
    vals[n]  = has ? (-l * lower * 0.5f) : 0.f;
}

// K3: single-block scan of flags + direct scatter of the <=N non-zeros into
// the (already zeroed) extra block: extra[run][n] = vals[n] for crossing n.
__global__ __launch_bounds__(256) void k_scan_scatter(
    const int* __restrict__ flags, const float* __restrict__ vals,
    float* __restrict__ outExtra, int N)
{
    __shared__ int waveSums[4];
    const int t    = threadIdx.x;
    const int per  = N / 256;         // 32
    const int base = t * per;
    int f[32];
    int cnt = 0;
    #pragma unroll
    for (int i = 0; i < 32; ++i) { f[i] = flags[base + i]; cnt += f[i]; }
    // inclusive shfl scan across the 64-lane wave
    const int lane = t & 63;
    const int wid  = t >> 6;
    int v = cnt;
    #pragma unroll
    for (int off = 1; off < 64; off <<= 1) {
        const int u = __shfl_up(v, off, 64);
        if (lane >= off) v += u;
    }
    if (lane == 63) waveSums[wid] = v;
    __syncthreads();
    int wadd = 0;
    for (int w = 0; w < wid; ++w) wadd += waveSums[w];
    int run = v - cnt + wadd;         // exclusive prefix for this thread
    #pragma unroll
    for (int i = 0; i < 32; ++i) {
        if (f[i]) {
            outExtra[(size_t)run * N + (base + i)] = vals[base + i];
            run += 1;
        }
    }
}

extern "C" void kernel_launch(void* const* d_in, const int* in_sizes, int n_in,
                              void* d_out, int out_size, void* d_ws, size_t ws_size,
                              hipStream_t stream) {
    const float* x   = (const float*)d_in[0];
    const float* lam = (const float*)d_in[1];
    float* out = (float*)d_out;

    const int N  = in_sizes[1];            // 8192
    const int E1 = in_sizes[0] / N;        // 2049
    const int E  = E1 - 1;                 // 2048

    const int PBY = 32;                    // keep accumulation order (absmax=0)
    float* outExtra = out + (size_t)E1 * N;

    float* partials = (float*)d_ws;                     // [PBY][N]
    float* vals     = partials + (size_t)PBY * N;       // [N]
    int*   flags    = (int*)(vals + N);                 // [N]

    dim3 blk(256);

    const int k1Blocks = (N / 1024) * PBY;   // 256
    const int fillRpb  = 8;                  // 1024 fill blocks, 256 KB linear each
    const int fillBlocks = N / fillRpb;
    hipLaunchKernelGGL(k_mega, dim3(k1Blocks + fillBlocks), blk, 0, stream,
                       x, lam, out, partials, outExtra,
                       N, E / PBY, k1Blocks, fillRpb);

    hipLaunchKernelGGL(k_stats, dim3(N / 256), blk, 0, stream,
                       x, lam, partials, out, vals, flags, N, PBY);

    hipLaunchKernelGGL(k_scan_scatter, dim3(1), blk, 0, stream,
                       flags, vals, outExtra, N);
}